// Round 6
// baseline (255.154 us; speedup 1.0000x reference)
//
#include <hip/hip_runtime.h>

// RandHashProj: out[b, sel[r]] += sign[r] * x[b, r]
// proj (8192x8192 f32): exactly one +-1 per row; per-column count ~ Poisson(1).
// R6: width-4 ELL (ushort4/column) + overflow; PERSISTENT gather blocks:
//   512 blocks x 512 thr, each owns 8 batch rows = 4 groups of 2 rows,
//   double-buffered bf16-pair LDS (2x32 KiB), ELL cached in VGPRs,
//   prefetch next group's x into regs during compute (issue-early/write-late).
// Overflow handled by a separate tiny kernel (plain RMW, no ordering hazard).
// ELL entry: (r<<2)|(sign<<1)|1 ; 0 = empty.

#define OUT_FEAT 8192
#define IN_FEAT 8192
#define OUT_SHIFT 13  // log2(OUT_FEAT)
#define GBLK 512
#define GTHR 512

// ---- Kernel A: scan proj; fill ELL + overflow list ----
__global__ void extract_fill(const float4* __restrict__ proj4, int* __restrict__ cur,
                             int* __restrict__ onum, unsigned int* __restrict__ ovals,
                             unsigned short* __restrict__ ell, long n4) {
    long stride = (long)gridDim.x * blockDim.x;
    for (long i = (long)blockIdx.x * blockDim.x + threadIdx.x; i < n4; i += stride) {
        float4 v = proj4[i];
        if (v.x != 0.f || v.y != 0.f || v.z != 0.f || v.w != 0.f) {
            float a[4] = {v.x, v.y, v.z, v.w};
            #pragma unroll
            for (int k = 0; k < 4; ++k) {
                if (a[k] != 0.f) {
                    long idx = i * 4 + k;
                    int r = (int)(idx >> OUT_SHIFT);
                    int c = (int)(idx & (OUT_FEAT - 1));
                    int sg = (a[k] < 0.f) ? 1 : 0;
                    int pos = atomicAdd(&cur[c], 1);
                    if (pos < 4) {
                        ell[c * 4 + pos] = (unsigned short)((r << 2) | (sg << 1) | 1);
                    } else {
                        int o = atomicAdd(onum, 1);
                        ovals[o] = ((unsigned int)c << 14) | ((unsigned int)r << 1) | sg;
                    }
                }
            }
        }
    }
}

__device__ __forceinline__ unsigned int pack_bf16(float a, float b) {
    unsigned int ua = __builtin_bit_cast(unsigned int, a);
    unsigned int ub = __builtin_bit_cast(unsigned int, b);
    ua = (ua + 0x8000u) >> 16;
    ub = (ub + 0x8000u) & 0xFFFF0000u;
    return ub | ua;
}

// ---- Kernel B: persistent gather, 2 rows/group, double-buffered LDS ----
__global__ void __launch_bounds__(GTHR, 4) gather_kernel(const float4* __restrict__ x4,
        const ushort4* __restrict__ ell4, float* __restrict__ out, int batch) {
    __shared__ unsigned int xs[2][IN_FEAT];  // 2 x 32 KiB ping-pong
    int t = threadIdx.x;

    // Cache the full ELL slice for this thread's 16 columns in registers.
    ushort4 e[16];
    #pragma unroll
    for (int j = 0; j < 16; ++j) e[j] = ell4[(j << 9) | t];

    int rpb = batch / gridDim.x;          // 8 rows per block
    int b0 = blockIdx.x * rpb;
    int ngrp = rpb >> 1;                  // 4 groups of 2 rows

    // Prologue: stage group 0.
    float4 pa[4], pb[4];
    {
        const float4* xr = x4 + (size_t)b0 * (IN_FEAT / 4);
        #pragma unroll
        for (int i = 0; i < 4; ++i) {
            pa[i] = xr[(i << 9) | t];
            pb[i] = xr[(IN_FEAT / 4) + ((i << 9) | t)];
        }
        #pragma unroll
        for (int i = 0; i < 4; ++i) {
            int idx = (i << 9) | t;
            uint4 p;
            p.x = pack_bf16(pa[i].x, pb[i].x);
            p.y = pack_bf16(pa[i].y, pb[i].y);
            p.z = pack_bf16(pa[i].z, pb[i].z);
            p.w = pack_bf16(pa[i].w, pb[i].w);
            ((uint4*)xs[0])[idx] = p;
        }
    }
    __syncthreads();

    for (int g = 0; g < ngrp; ++g) {
        // Issue next group's x loads into registers (overlap with compute).
        if (g + 1 < ngrp) {
            const float4* xn = x4 + (size_t)(b0 + 2 * (g + 1)) * (IN_FEAT / 4);
            #pragma unroll
            for (int i = 0; i < 4; ++i) {
                pa[i] = xn[(i << 9) | t];
                pb[i] = xn[(IN_FEAT / 4) + ((i << 9) | t)];
            }
        }

        // Compute group g from buf[g&1].
        const unsigned int* xsg = xs[g & 1];
        float* orow0 = out + (size_t)(b0 + 2 * g) * OUT_FEAT;
        float* orow1 = orow0 + OUT_FEAT;
        #pragma unroll
        for (int j = 0; j < 16; ++j) {
            int c = (j << 9) | t;
            float s0 = 0.f, s1 = 0.f;
            #pragma unroll
            for (int k = 0; k < 4; ++k) {
                unsigned short ek = (k == 0) ? e[j].x : (k == 1) ? e[j].y
                                  : (k == 2) ? e[j].z : e[j].w;
                unsigned int u = xsg[ek >> 2];            // ds_read_b32
                float wt = (ek & 1) ? ((ek & 2) ? -1.f : 1.f) : 0.f;
                s0 = fmaf(wt, __builtin_bit_cast(float, u << 16), s0);
                s1 = fmaf(wt, __builtin_bit_cast(float, u & 0xFFFF0000u), s1);
            }
            orow0[c] = s0;    // wave-contiguous 256B stores
            orow1[c] = s1;
        }

        // Write prefetched rows into the other buffer (write-late).
        if (g + 1 < ngrp) {
            unsigned int* xsn = xs[(g + 1) & 1];
            #pragma unroll
            for (int i = 0; i < 4; ++i) {
                int idx = (i << 9) | t;
                uint4 p;
                p.x = pack_bf16(pa[i].x, pb[i].x);
                p.y = pack_bf16(pa[i].y, pb[i].y);
                p.z = pack_bf16(pa[i].z, pb[i].z);
                p.w = pack_bf16(pa[i].w, pb[i].w);
                ((uint4*)xsn)[idx] = p;
            }
        }
        __syncthreads();      // one barrier per group
    }
}

// ---- Kernel C: overflow entries (~dozens). Plain RMW after gather. ----
__global__ void overflow_kernel(const float* __restrict__ x,
        const unsigned int* __restrict__ ovals, const int* __restrict__ onum_p,
        float* __restrict__ out, int batch) {
    int on = *onum_p;
    int b = blockIdx.x * blockDim.x + threadIdx.x;
    if (b >= batch || on == 0) return;
    const float* xrow = x + (size_t)b * IN_FEAT;
    float* orow = out + (size_t)b * OUT_FEAT;
    for (int m = 0; m < on; ++m) {
        unsigned int e = ovals[m];
        int c = (int)(e >> 14);
        int r = (int)((e >> 1) & (IN_FEAT - 1));
        float wt = (e & 1) ? -1.f : 1.f;
        orow[c] += wt * xrow[r];   // exact f32 for the rare tail
    }
}

extern "C" void kernel_launch(void* const* d_in, const int* in_sizes, int n_in,
                              void* d_out, int out_size, void* d_ws, size_t ws_size,
                              hipStream_t stream) {
    const float* x = (const float*)d_in[0];
    const float* proj = (const float*)d_in[1];
    float* out = (float*)d_out;

    const int out_feat = OUT_FEAT;
    long proj_elems = (long)in_sizes[1];
    int in_feat = (int)(proj_elems / out_feat);   // 8192
    int batch = in_sizes[0] / in_feat;            // 4096

    // ws layout (contiguous so ONE memset zeroes cur+onum+ell):
    // [cur 32 KiB][onum 4 B][pad 60 B][ell 64 KiB][ovals 32 KiB]
    char* w = (char*)d_ws;
    int* cur = (int*)w;
    int* onum = (int*)(w + 32 * 1024);
    unsigned short* ell = (unsigned short*)(w + 32 * 1024 + 64);
    unsigned int* ovals = (unsigned int*)(w + 96 * 1024 + 64);

    hipMemsetAsync(cur, 0, 96 * 1024 + 64, stream);

    long n4 = proj_elems / 4;
    extract_fill<<<8192, 256, 0, stream>>>((const float4*)proj, cur, onum, ovals, ell, n4);
    gather_kernel<<<GBLK, GTHR, 0, stream>>>((const float4*)x, (const ushort4*)ell,
                                             out, batch);
    overflow_kernel<<<(batch + 255) / 256, 256, 0, stream>>>(x, ovals, onum, out, batch);
}

// Round 7
// 243.512 us; speedup vs baseline: 1.0478x; 1.0478x over previous
//
#include <hip/hip_runtime.h>

// RandHashProj: out[b, sel[r]] += sign[r] * x[b, r]
// proj (8192x8192 f32): exactly one +-1 per row; per-column count ~ Poisson(1).
// R7 (R5 skeleton): width-2 ELL (2 ushorts = 1 uint per column) + overflow
// (~850 entries, inline while out rows are L2-hot). Empty slot -> zero-slot
// trick: entry r=8192 points at xs[8192]=0.0, sign folded branchlessly.
// Gather: 2 batch rows/block, bf16-pair-packed LDS (32 KiB), depth-2 ELL
// pipeline, fully unrolled. No register arrays (R6 spill lesson).
// ELL entry (ushort): (r<<2) | (sign<<1);  empty = 0x8000 (r=8192).

#define OUT_FEAT 8192
#define IN_FEAT 8192
#define OUT_SHIFT 13  // log2(OUT_FEAT)
#define EMPTY_PAIR 0x80008000u

// ---- Kernel 0: init cur/onum/ell (pattern fill, memset can't do 0x8000) ----
__global__ void init_kernel(int* __restrict__ cur, int* __restrict__ onum,
                            unsigned int* __restrict__ ellw) {
    int i = blockIdx.x * blockDim.x + threadIdx.x;
    if (i < OUT_FEAT) {
        cur[i] = 0;
        ellw[i] = EMPTY_PAIR;
    }
    if (i == 0) *onum = 0;
}

// ---- Kernel A: scan proj; fill width-2 ELL + overflow list ----
__global__ void extract_fill(const float4* __restrict__ proj4, int* __restrict__ cur,
                             int* __restrict__ onum, unsigned int* __restrict__ ovals,
                             unsigned int* __restrict__ ellw, long n4) {
    long stride = (long)gridDim.x * blockDim.x;
    for (long i = (long)blockIdx.x * blockDim.x + threadIdx.x; i < n4; i += stride) {
        float4 v = proj4[i];
        if (v.x != 0.f || v.y != 0.f || v.z != 0.f || v.w != 0.f) {
            float a[4] = {v.x, v.y, v.z, v.w};
            #pragma unroll
            for (int k = 0; k < 4; ++k) {
                if (a[k] != 0.f) {
                    long idx = i * 4 + k;
                    int r = (int)(idx >> OUT_SHIFT);
                    int c = (int)(idx & (OUT_FEAT - 1));
                    int sg = (a[k] < 0.f) ? 1 : 0;
                    int pos = atomicAdd(&cur[c], 1);
                    if (pos < 2) {
                        ((unsigned short*)ellw)[c * 2 + pos] =
                            (unsigned short)((r << 2) | (sg << 1));
                    } else {
                        int o = atomicAdd(onum, 1);
                        ovals[o] = ((unsigned int)c << 14) | ((unsigned int)r << 1) | sg;
                    }
                }
            }
        }
    }
}

__device__ __forceinline__ unsigned int pack_bf16(float a, float b) {
    unsigned int ua = __builtin_bit_cast(unsigned int, a);
    unsigned int ub = __builtin_bit_cast(unsigned int, b);
    ua = (ua + 0x8000u) >> 16;
    ub = (ub + 0x8000u) & 0xFFFF0000u;
    return ub | ua;
}

// ---- Kernel B: gather, 2 rows/block, bf16-packed LDS + zero slot ----
__global__ void __launch_bounds__(512, 8) gather2_kernel(const float4* __restrict__ x4,
        const unsigned int* __restrict__ ellw, const unsigned int* __restrict__ ovals,
        const int* __restrict__ onum_p, float* __restrict__ out) {
    __shared__ unsigned int xs[IN_FEAT + 16];  // +zero slot at [IN_FEAT]
    int t = threadIdx.x;
    int b0 = blockIdx.x * 2;
    const float4* xr0 = x4 + (size_t)b0 * (IN_FEAT / 4);
    const float4* xr1 = xr0 + (IN_FEAT / 4);
    #pragma unroll
    for (int i = 0; i < 4; ++i) {
        int idx = (i << 9) | t;
        float4 a = xr0[idx];
        float4 b = xr1[idx];
        uint4 p;
        p.x = pack_bf16(a.x, b.x);
        p.y = pack_bf16(a.y, b.y);
        p.z = pack_bf16(a.z, b.z);
        p.w = pack_bf16(a.w, b.w);
        ((uint4*)xs)[idx] = p;
    }
    if (t == 0) xs[IN_FEAT] = 0u;  // zero slot for empty entries
    __syncthreads();

    float* orow0 = out + (size_t)b0 * OUT_FEAT;
    float* orow1 = orow0 + OUT_FEAT;
    int lane = t & 63;
    int wv = t >> 6;          // 8 waves
    int cbase = (wv << 10) | lane;

    unsigned int eu = ellw[cbase];   // depth-2 pipeline head
    #pragma unroll
    for (int j = 0; j < 16; ++j) {
        unsigned int e = eu;
        if (j < 15) eu = ellw[cbase + ((j + 1) << 6)];
        int c = cbase + (j << 6);
        float s0, s1;
        {   // slot 0 (low ushort)
            unsigned int e0 = e & 0xFFFFu;
            unsigned int u = *(const unsigned int*)((const char*)xs + (e0 & 0xFFFCu));
            float wt = __builtin_bit_cast(float, 0x3F800000u | ((e0 << 30) & 0x80000000u));
            s0 = wt * __builtin_bit_cast(float, u << 16);
            s1 = wt * __builtin_bit_cast(float, u & 0xFFFF0000u);
        }
        {   // slot 1 (high ushort)
            unsigned int e1 = e >> 16;
            unsigned int u = *(const unsigned int*)((const char*)xs + (e1 & 0xFFFCu));
            float wt = __builtin_bit_cast(float, 0x3F800000u | ((e1 << 30) & 0x80000000u));
            s0 = fmaf(wt, __builtin_bit_cast(float, u << 16), s0);
            s1 = fmaf(wt, __builtin_bit_cast(float, u & 0xFFFF0000u), s1);
        }
        orow0[c] = s0;   // wave writes 256B contiguous
        orow1[c] = s1;
    }

    // Overflow (~850 entries). Barrier drains plain stores (vmcnt(0) before
    // s_barrier) so the atomics below can't be overwritten. Out rows are
    // still L2-resident in this XCD.
    __syncthreads();
    int on = *onum_p;
    for (int m = t; m < on; m += 512) {
        unsigned int e = ovals[m];
        int c = (int)(e >> 14);
        int r = (int)((e >> 1) & (IN_FEAT - 1));
        float wt = (e & 1) ? -1.f : 1.f;
        unsigned int u = xs[r];
        atomicAdd(&orow0[c], wt * __builtin_bit_cast(float, u << 16));
        atomicAdd(&orow1[c], wt * __builtin_bit_cast(float, u & 0xFFFF0000u));
    }
}

extern "C" void kernel_launch(void* const* d_in, const int* in_sizes, int n_in,
                              void* d_out, int out_size, void* d_ws, size_t ws_size,
                              hipStream_t stream) {
    const float* x = (const float*)d_in[0];
    const float* proj = (const float*)d_in[1];
    float* out = (float*)d_out;

    const int out_feat = OUT_FEAT;
    long proj_elems = (long)in_sizes[1];
    int in_feat = (int)(proj_elems / out_feat);   // 8192
    int batch = in_sizes[0] / in_feat;            // 4096

    // ws layout: [cur 32 KiB][onum 4 B][pad 60 B][ellw 32 KiB][ovals 32 KiB]
    char* w = (char*)d_ws;
    int* cur = (int*)w;
    int* onum = (int*)(w + 32 * 1024);
    unsigned int* ellw = (unsigned int*)(w + 32 * 1024 + 64);
    unsigned int* ovals = (unsigned int*)(w + 64 * 1024 + 64);

    init_kernel<<<OUT_FEAT / 256, 256, 0, stream>>>(cur, onum, ellw);
    long n4 = proj_elems / 4;
    extract_fill<<<8192, 256, 0, stream>>>((const float4*)proj, cur, onum, ovals, ellw, n4);
    gather2_kernel<<<batch / 2, 512, 0, stream>>>((const float4*)x, ellw, ovals, onum, out);
}

// Round 8
// 120.825 us; speedup vs baseline: 2.1118x; 2.0154x over previous
//
#include <hip/hip_runtime.h>

// RandHashProj: out[b, sel[r]] += sign[r] * x[b, r]
// proj (8192x8192 f32): exactly one +-1 per row; per-column count ~ Poisson(1).
// R8: width-4 ELL (ushort4/column, overflow ~35 entries inline) + zero-slot
// branchless decode + ELL slice cached in REGISTERS up-front (32 VGPRs,
// launch_bounds(512,4) -> 128-VGPR cap, no other reg arrays; R6 spill lesson).
// Gather: 2 batch rows/block, bf16-pair-packed LDS (32 KiB + zero slot).
// ELL entry (ushort): (r<<2) | (sign<<1);  empty = 0x8000 (r=8192 -> xs=0).

#define OUT_FEAT 8192
#define IN_FEAT 8192
#define OUT_SHIFT 13  // log2(OUT_FEAT)
#define EMPTY_PAIR 0x80008000u

// ---- Kernel 0: init cur/onum/ell (pattern fill; memset can't write 0x8000) ----
__global__ void init_kernel(int* __restrict__ cur, int* __restrict__ onum,
                            unsigned int* __restrict__ ellw) {
    int i = blockIdx.x * blockDim.x + threadIdx.x;
    if (i < OUT_FEAT) {
        cur[i] = 0;
        ellw[2 * i] = EMPTY_PAIR;      // slots 0,1
        ellw[2 * i + 1] = EMPTY_PAIR;  // slots 2,3
    }
    if (i == 0) *onum = 0;
}

// ---- Kernel A: scan proj; fill width-4 ELL + overflow list ----
__global__ void extract_fill(const float4* __restrict__ proj4, int* __restrict__ cur,
                             int* __restrict__ onum, unsigned int* __restrict__ ovals,
                             unsigned short* __restrict__ ell, long n4) {
    long stride = (long)gridDim.x * blockDim.x;
    for (long i = (long)blockIdx.x * blockDim.x + threadIdx.x; i < n4; i += stride) {
        float4 v = proj4[i];
        if (v.x != 0.f || v.y != 0.f || v.z != 0.f || v.w != 0.f) {
            float a[4] = {v.x, v.y, v.z, v.w};
            #pragma unroll
            for (int k = 0; k < 4; ++k) {
                if (a[k] != 0.f) {
                    long idx = i * 4 + k;
                    int r = (int)(idx >> OUT_SHIFT);
                    int c = (int)(idx & (OUT_FEAT - 1));
                    int sg = (a[k] < 0.f) ? 1 : 0;
                    int pos = atomicAdd(&cur[c], 1);
                    if (pos < 4) {
                        ell[c * 4 + pos] = (unsigned short)((r << 2) | (sg << 1));
                    } else {
                        int o = atomicAdd(onum, 1);
                        ovals[o] = ((unsigned int)c << 14) | ((unsigned int)r << 1) | sg;
                    }
                }
            }
        }
    }
}

__device__ __forceinline__ unsigned int pack_bf16(float a, float b) {
    unsigned int ua = __builtin_bit_cast(unsigned int, a);
    unsigned int ub = __builtin_bit_cast(unsigned int, b);
    ua = (ua + 0x8000u) >> 16;
    ub = (ub + 0x8000u) & 0xFFFF0000u;
    return ub | ua;
}

// one ELL slot -> fma into s0/s1 (branchless; empty hits xs[8192]=0)
#define SLOT(ek)                                                                 \
    {                                                                            \
        unsigned int _e = (ek);                                                  \
        unsigned int _u = *(const unsigned int*)((const char*)xs + (_e & 0xFFFCu)); \
        float _wt = __builtin_bit_cast(float, 0x3F800000u | ((_e << 30) & 0x80000000u)); \
        s0 = fmaf(_wt, __builtin_bit_cast(float, _u << 16), s0);                 \
        s1 = fmaf(_wt, __builtin_bit_cast(float, _u & 0xFFFF0000u), s1);         \
    }

// ---- Kernel B: gather, 2 rows/block, bf16-packed LDS, ELL in registers ----
__global__ void __launch_bounds__(512, 4) gather2_kernel(const float4* __restrict__ x4,
        const ushort4* __restrict__ ell4, const unsigned int* __restrict__ ovals,
        const int* __restrict__ onum_p, float* __restrict__ out) {
    __shared__ unsigned int xs[IN_FEAT + 16];  // + zero slot at [IN_FEAT]
    int t = threadIdx.x;
    int lane = t & 63;
    int wv = t >> 6;                 // 8 waves
    int cbase = (wv << 10) | lane;

    // Load this thread's 16 ELL columns into registers (one independent burst).
    ushort4 ev[16];
    #pragma unroll
    for (int j = 0; j < 16; ++j) ev[j] = ell4[cbase + (j << 6)];

    int b0 = blockIdx.x * 2;
    const float4* xr0 = x4 + (size_t)b0 * (IN_FEAT / 4);
    const float4* xr1 = xr0 + (IN_FEAT / 4);
    #pragma unroll
    for (int i = 0; i < 4; ++i) {
        int idx = (i << 9) | t;
        float4 a = xr0[idx];
        float4 b = xr1[idx];
        uint4 p;
        p.x = pack_bf16(a.x, b.x);
        p.y = pack_bf16(a.y, b.y);
        p.z = pack_bf16(a.z, b.z);
        p.w = pack_bf16(a.w, b.w);
        ((uint4*)xs)[idx] = p;
    }
    if (t == 0) xs[IN_FEAT] = 0u;    // zero slot for empty entries
    __syncthreads();

    float* orow0 = out + (size_t)b0 * OUT_FEAT;
    float* orow1 = orow0 + OUT_FEAT;

    #pragma unroll
    for (int j = 0; j < 16; ++j) {
        int c = cbase + (j << 6);
        float s0 = 0.f, s1 = 0.f;
        SLOT(ev[j].x);
        SLOT(ev[j].y);
        SLOT(ev[j].z);
        SLOT(ev[j].w);
        orow0[c] = s0;   // wave writes 256B contiguous
        orow1[c] = s1;
    }

    // Overflow (~35 entries total). Barrier drains plain stores first.
    __syncthreads();
    int on = *onum_p;
    for (int m = t; m < on; m += 512) {
        unsigned int e = ovals[m];
        int c = (int)(e >> 14);
        int r = (int)((e >> 1) & (IN_FEAT - 1));
        float wt = (e & 1) ? -1.f : 1.f;
        unsigned int u = xs[r];
        atomicAdd(&orow0[c], wt * __builtin_bit_cast(float, u << 16));
        atomicAdd(&orow1[c], wt * __builtin_bit_cast(float, u & 0xFFFF0000u));
    }
}

extern "C" void kernel_launch(void* const* d_in, const int* in_sizes, int n_in,
                              void* d_out, int out_size, void* d_ws, size_t ws_size,
                              hipStream_t stream) {
    const float* x = (const float*)d_in[0];
    const float* proj = (const float*)d_in[1];
    float* out = (float*)d_out;

    const int out_feat = OUT_FEAT;
    long proj_elems = (long)in_sizes[1];
    int in_feat = (int)(proj_elems / out_feat);   // 8192
    int batch = in_sizes[0] / in_feat;            // 4096

    // ws layout: [cur 32 KiB][onum 4 B][pad 60 B][ell 64 KiB][ovals 32 KiB]
    char* w = (char*)d_ws;
    int* cur = (int*)w;
    int* onum = (int*)(w + 32 * 1024);
    unsigned int* ellw = (unsigned int*)(w + 32 * 1024 + 64);
    unsigned int* ovals = (unsigned int*)(w + 96 * 1024 + 64);

    init_kernel<<<OUT_FEAT / 256, 256, 0, stream>>>(cur, onum, ellw);
    long n4 = proj_elems / 4;
    extract_fill<<<8192, 256, 0, stream>>>((const float4*)proj, cur, onum, ovals,
                                           (unsigned short*)ellw, n4);
    gather2_kernel<<<batch / 2, 512, 0, stream>>>((const float4*)x, (const ushort4*)ellw,
                                                  ovals, onum, out);
}